// Round 1
// baseline (615.983 us; speedup 1.0000x reference)
//
#include <hip/hip_runtime.h>
#include <cstdint>

#define T_DIM 1000
#define B_DIM 64
#define C_DIM 256
#define L_DIM 100
#define S_DIM (2 * L_DIM + 1) /* 201 */
#define NEG (-1e30f)

__device__ __forceinline__ float lse2(float x, float y) {
    float m = fmaxf(x, y);
    float s = __expf(x - m) + __expf(y - m);
    return m + __logf(s);
}

__device__ __forceinline__ float lse3(float x, float y, float z, bool allow) {
    float zz = allow ? z : NEG;
    float m = fmaxf(fmaxf(x, y), zz);
    float s = __expf(x - m) + __expf(y - m) + (allow ? __expf(z - m) : 0.0f);
    return m + __logf(s);
}

// Fused kernel: blocks [0,B): CTC alpha recursion, one wave per batch sample.
//               blocks [B,2B): mean-over-time exp(log_probs) per (b,c).
__global__ __launch_bounds__(256) void ctc_fused(
        const float* __restrict__ lp,       // (T,B,C)
        const int* __restrict__ tgt,        // (B*L,)
        const int* __restrict__ il,         // (B,)
        const int* __restrict__ tl,         // (B,)
        float* __restrict__ ws_mean,        // (B,C)
        float* __restrict__ ws_loss) {      // (B,)
    const int blk = blockIdx.x;
    const size_t rstride = (size_t)B_DIM * C_DIM;

    if (blk >= B_DIM) {
        // ---- mean_probs pass: batch b, thread = class c ----
        const int b = blk - B_DIM;
        const int c = threadIdx.x;
        const float* p = lp + (size_t)b * C_DIM + c;
        float s0 = 0.f, s1 = 0.f, s2 = 0.f, s3 = 0.f;
        for (int t = 0; t < T_DIM; t += 4) {
            float v0 = p[(size_t)(t + 0) * rstride];
            float v1 = p[(size_t)(t + 1) * rstride];
            float v2 = p[(size_t)(t + 2) * rstride];
            float v3 = p[(size_t)(t + 3) * rstride];
            s0 += __expf(v0);
            s1 += __expf(v1);
            s2 += __expf(v2);
            s3 += __expf(v3);
        }
        ws_mean[b * C_DIM + c] = (s0 + s1 + s2 + s3) * (1.0f / T_DIM);
        return;
    }

    // ---- CTC pass: one wave (threads 0..63) per batch sample ----
    if (threadIdx.x >= 64) return;
    const int b = blk;
    const int lane = threadIdx.x;
    const int* trow = tgt + b * L_DIM;
    const int ilen = il[b];
    const int tlen = tl[b];

    // lane holds extended states s0i..s0i+3 (blank,target,blank,target)
    const int s0i = 4 * lane;
    const bool v0 = (s0i + 0) < S_DIM;
    const bool v1 = (s0i + 1) < S_DIM;
    const bool v2 = (s0i + 2) < S_DIM;
    const bool v3 = (s0i + 3) < S_DIM;

    const int i1 = 2 * lane;      // target idx for slot 1 (state 4i+1)
    const int i3 = 2 * lane + 1;  // target idx for slot 3 (state 4i+3)
    const int c1 = (i1 < L_DIM) ? trow[i1] : 0;
    const int c3 = (i3 < L_DIM) ? trow[i3] : 0;
    const int c1m = (i1 >= 1 && i1 - 1 < L_DIM) ? trow[i1 - 1] : -1;
    const bool allow1 = (i1 >= 1) && (c1 != c1m); // skip into state 4i+1
    const bool allow3 = (c3 != c1);               // skip into state 4i+3 (s>=3 always)

    const float* rowbase = lp + (size_t)b * C_DIM;

    // t = 0 init: alpha[0] = lp[0,b,blank], alpha[1] = lp[0,b,tgt[0]]
    float a0 = NEG, a1 = NEG, a2 = NEG, a3 = NEG;
    if (lane == 0) {
        a0 = rowbase[0];
        a1 = rowbase[c1];
    }

    // depth-4 register prefetch of emit values
    float eb[4], e1[4], e3[4];
#pragma unroll
    for (int d = 0; d < 4; ++d) {
        int t = 1 + d;
        if (t < ilen) {
            const float* r = rowbase + (size_t)t * rstride;
            eb[d] = r[0];
            e1[d] = r[c1];
            e3[d] = r[c3];
        } else {
            eb[d] = 0.f; e1[d] = 0.f; e3[d] = 0.f;
        }
    }

    for (int tb = 1; tb < ilen; tb += 4) {
#pragma unroll
        for (int d = 0; d < 4; ++d) {
            const int t = tb + d;
            if (t < ilen) {
                const float ebc = eb[d], e1c = e1[d], e3c = e3[d];
                const int tp = t + 4;
                if (tp < ilen) {
                    const float* r = rowbase + (size_t)tp * rstride;
                    eb[d] = r[0];
                    e1[d] = r[c1];
                    e3[d] = r[c3];
                }
                float p3 = __shfl_up(a3, 1, 64); // state 4i-1 from prev lane
                if (lane == 0) p3 = NEG;
                const float n0 = lse2(a0, p3) + ebc;              // even: no skip
                const float n1 = lse3(a1, a0, p3, allow1) + e1c;  // odd
                const float n2 = lse2(a2, a1) + ebc;              // even: no skip
                const float n3 = lse3(a3, a2, a1, allow3) + e3c;  // odd
                a0 = v0 ? n0 : NEG;
                a1 = v1 ? n1 : NEG;
                a2 = v2 ? n2 : NEG;
                a3 = v3 ? n3 : NEG;
            }
        }
    }

    // final: ll = logaddexp(alpha[2*tl], alpha[2*tl-1])
    const int s_hi = 2 * tlen;
    const int s_lo = 2 * tlen - 1;
    const int slot_hi = s_hi & 3, lane_hi = min(s_hi >> 2, 63);
    const int slot_lo = s_lo & 3, lane_lo = min(s_lo >> 2, 63);
    float ch = (slot_hi == 0) ? a0 : (slot_hi == 1) ? a1 : (slot_hi == 2) ? a2 : a3;
    float cl = (slot_lo == 0) ? a0 : (slot_lo == 1) ? a1 : (slot_lo == 2) ? a2 : a3;
    float vh = __shfl(ch, lane_hi, 64);
    float vl = __shfl(cl, lane_lo, 64);
    if (lane == 0) {
        float ll = lse2(vh, vl);
        ws_loss[b] = (ll > NEG * 0.5f) ? -ll : 0.0f; // zero_infinity
    }
}

// out = (sum_j focal_j / (B*L)) * (sum_b loss_b / B)
__global__ __launch_bounds__(256) void ctc_finalize(
        const float* __restrict__ ws_mean, const float* __restrict__ ws_loss,
        const int* __restrict__ tgt, float* __restrict__ out) {
    const int tid = threadIdx.x;
    float fsum = 0.f;
#pragma unroll
    for (int k = 0; k < (B_DIM * L_DIM) / 256; ++k) {
        const int j = tid + k * 256;
        const int b = j / L_DIM;
        const int c = tgt[j];
        const float p = ws_mean[b * C_DIM + c];
        const float w = 1.0f - p;
        fsum += w * w;
    }
    float lsum = (tid < B_DIM) ? ws_loss[tid] : 0.f;
#pragma unroll
    for (int off = 32; off > 0; off >>= 1) {
        fsum += __shfl_down(fsum, off, 64);
        lsum += __shfl_down(lsum, off, 64);
    }
    __shared__ float sf[4], sl[4];
    const int w = tid >> 6;
    if ((tid & 63) == 0) { sf[w] = fsum; sl[w] = lsum; }
    __syncthreads();
    if (tid == 0) {
        const float F = sf[0] + sf[1] + sf[2] + sf[3];
        const float Lo = sl[0] + sl[1] + sl[2] + sl[3];
        out[0] = (F / (float)(B_DIM * L_DIM)) * (Lo / (float)B_DIM);
    }
}

extern "C" void kernel_launch(void* const* d_in, const int* in_sizes, int n_in,
                              void* d_out, int out_size, void* d_ws, size_t ws_size,
                              hipStream_t stream) {
    const float* lp = (const float*)d_in[0];
    const int* tgt = (const int*)d_in[1];
    const int* il = (const int*)d_in[2];
    const int* tl = (const int*)d_in[3];
    float* ws_mean = (float*)d_ws;               // B*C floats
    float* ws_loss = ws_mean + B_DIM * C_DIM;    // B floats

    ctc_fused<<<dim3(2 * B_DIM), dim3(256), 0, stream>>>(lp, tgt, il, tl, ws_mean, ws_loss);
    ctc_finalize<<<dim3(1), dim3(256), 0, stream>>>(ws_mean, ws_loss, tgt, (float*)d_out);
}

// Round 3
// 202.814 us; speedup vs baseline: 3.0372x; 3.0372x over previous
//
#include <hip/hip_runtime.h>
#include <cstdint>

#define T_DIM 1000
#define B_DIM 64
#define C_DIM 256
#define L_DIM 100
#define S_DIM (2 * L_DIM + 1) /* 201 */
#define RING 16
#define MEAN_SLICES 8
#define MEAN_ROWS (T_DIM / MEAN_SLICES) /* 125 */

// Fused kernel:
//   blocks [0,B): CTC alpha recursion in LINEAR space, one wave per sample.
//   blocks [B, B+8*B): mean-over-time exp(log_probs), 8 time-slices per sample,
//                      atomicAdd into ws_mean (zeroed by memsetAsync in kernel_launch).
__global__ __launch_bounds__(256) void ctc_fused(
        const float* __restrict__ lp,       // (T,B,C)
        const int* __restrict__ tgt,        // (B*L,)
        const int* __restrict__ il,         // (B,)
        const int* __restrict__ tl,         // (B,)
        float* __restrict__ ws_mean,        // (B,C) zero-initialized
        float* __restrict__ ws_loss) {      // (B,)
    const int blk = blockIdx.x;
    const uint32_t rstride = B_DIM * C_DIM; // elements per time row

    if (blk >= B_DIM) {
        // ---- mean_probs pass ----
        const int mb = blk - B_DIM;
        const int b = mb >> 3;
        const int slice = mb & 7;
        const int c = threadIdx.x;
        const float* p = lp + (size_t)b * C_DIM + c + (size_t)(slice * MEAN_ROWS) * rstride;
        float s0 = 0.f, s1 = 0.f, s2 = 0.f, s3 = 0.f, s4 = 0.f;
        for (int t = 0; t < MEAN_ROWS; t += 5) {
            s0 += __expf(p[(size_t)(t + 0) * rstride]);
            s1 += __expf(p[(size_t)(t + 1) * rstride]);
            s2 += __expf(p[(size_t)(t + 2) * rstride]);
            s3 += __expf(p[(size_t)(t + 3) * rstride]);
            s4 += __expf(p[(size_t)(t + 4) * rstride]);
        }
        atomicAdd(&ws_mean[b * C_DIM + c], (s0 + s1 + s2 + s3 + s4) * (1.0f / T_DIM));
        return;
    }

    // ---- CTC pass: one wave (threads 0..63) per batch sample ----
    if (threadIdx.x >= 64) return;
    const int b = blk;
    const int lane = threadIdx.x;
    const int* trow = tgt + b * L_DIM;
    const int ilen = il[b];
    const int tlen = tl[b];

    // lane holds extended states 4i..4i+3 (blank,target,blank,target)
    const int i1 = 2 * lane;      // target idx for slot 1 (state 4i+1)
    const int i3 = 2 * lane + 1;  // target idx for slot 3 (state 4i+3)
    const int c1 = (i1 < L_DIM) ? trow[i1] : 0;
    const int c3 = (i3 < L_DIM) ? trow[i3] : 0;
    const int c1m = (i1 >= 1 && i1 - 1 < L_DIM) ? trow[i1 - 1] : -1;
    const float m1 = ((i1 >= 1) && (c1 != c1m)) ? 1.0f : 0.0f; // skip into 4i+1
    const float m3 = (c3 != c1) ? 1.0f : 0.0f;                 // skip into 4i+3

    // validity masks (state index < S). Invalid states MUST be zeroed at each
    // renorm: they form a blank-emitting chain whose mass grows ~e^{0.6}/step
    // relative to the valid max; unmasked it overflows to inf and NaNs the
    // whole wave through the renorm coupling (R2 failure).
    const float f0 = (4 * lane + 0 < S_DIM) ? 1.0f : 0.0f;
    const float f1 = (4 * lane + 1 < S_DIM) ? 1.0f : 0.0f;
    const float f2 = (4 * lane + 2 < S_DIM) ? 1.0f : 0.0f;
    const float f3 = (4 * lane + 3 < S_DIM) ? 1.0f : 0.0f;

    const float* base = lp + (size_t)b * C_DIM;

    // t=0 init (linear space)
    float a0 = 0.f, a1 = 0.f, a2 = 0.f, a3 = 0.f;
    {
        float i0 = __expf(base[0]);
        float i1v = __expf(base[c1]);
        if (lane == 0) { a0 = i0; a1 = i1v; }
    }
    float ls = 0.f; // accumulated log scale

    // register ring prefetch of raw log-prob values, 16 steps deep
    float rb[RING], r1[RING], r3[RING];
#pragma unroll
    for (int d = 0; d < RING; ++d) {
        int t = 1 + d; t = (t < ilen) ? t : (ilen - 1);
        const uint32_t ro = (uint32_t)t * rstride;
        rb[d] = base[ro];
        r1[d] = base[ro + (uint32_t)c1];
        r3[d] = base[ro + (uint32_t)c3];
    }

    const int pidx = ((lane - 1) & 63) << 2; // bpermute byte addr: prev lane

    int base_t = 1;
    for (; base_t + RING <= ilen; base_t += RING) {
#pragma unroll
        for (int d = 0; d < RING; ++d) {
            const float pb  = __expf(rb[d]);
            const float p1e = __expf(r1[d]);
            const float p3e = __expf(r3[d]);
            // refill this slot for step base_t + d + RING (clamped, unconditional)
            {
                int tp = base_t + d + RING; tp = (tp < ilen) ? tp : (ilen - 1);
                const uint32_t ro = (uint32_t)tp * rstride;
                rb[d] = base[ro];
                r1[d] = base[ro + (uint32_t)c1];
                r3[d] = base[ro + (uint32_t)c3];
            }
            // recursion
            float p3 = __int_as_float(__builtin_amdgcn_ds_bpermute(pidx, __float_as_int(a3)));
            p3 = (lane == 0) ? 0.f : p3;
            const float a01 = a0 + a1;
            const float n0 = (a0 + p3) * pb;
            const float n1 = fmaf(m1, p3, a01) * p1e;
            const float n2 = (a2 + a1) * pb;
            const float n3 = (fmaf(m3, a1, a2) + a3) * p3e;
            a0 = n0; a1 = n1; a2 = n2; a3 = n3;
            if ((d & 7) == 7) {
                // mask invalid states, then wave-wide renorm
                a0 *= f0; a1 *= f1; a2 *= f2; a3 *= f3;
                float mx = fmaxf(fmaxf(a0, a1), fmaxf(a2, a3));
#pragma unroll
                for (int off = 1; off < 64; off <<= 1)
                    mx = fmaxf(mx, __shfl_xor(mx, off, 64));
                const float inv = __builtin_amdgcn_rcpf(mx);
                ls -= __logf(inv); // record exactly the applied multiplier
                a0 *= inv; a1 *= inv; a2 *= inv; a3 *= inv;
            }
        }
    }

    // tail (< RING steps), values already resident in the ring
#pragma unroll
    for (int d = 0; d < RING - 1; ++d) {
        const int t = base_t + d;
        if (t < ilen) {
            const float pb  = __expf(rb[d]);
            const float p1e = __expf(r1[d]);
            const float p3e = __expf(r3[d]);
            float p3 = __int_as_float(__builtin_amdgcn_ds_bpermute(pidx, __float_as_int(a3)));
            p3 = (lane == 0) ? 0.f : p3;
            const float a01 = a0 + a1;
            const float n0 = (a0 + p3) * pb;
            const float n1 = fmaf(m1, p3, a01) * p1e;
            const float n2 = (a2 + a1) * pb;
            const float n3 = (fmaf(m3, a1, a2) + a3) * p3e;
            a0 = n0; a1 = n1; a2 = n2; a3 = n3;
            if ((d & 7) == 7) {
                a0 *= f0; a1 *= f1; a2 *= f2; a3 *= f3;
                float mx = fmaxf(fmaxf(a0, a1), fmaxf(a2, a3));
#pragma unroll
                for (int off = 1; off < 64; off <<= 1)
                    mx = fmaxf(mx, __shfl_xor(mx, off, 64));
                const float inv = __builtin_amdgcn_rcpf(mx);
                ls -= __logf(inv);
                a0 *= inv; a1 *= inv; a2 *= inv; a3 *= inv;
            }
        }
    }

    // final: ll = log(alpha[2*tl] + alpha[2*tl-1]) + ls
    const int s_hi = 2 * tlen;
    const int s_lo = 2 * tlen - 1;
    const int slot_hi = s_hi & 3, lane_hi = min(s_hi >> 2, 63);
    const int slot_lo = s_lo & 3, lane_lo = min(s_lo >> 2, 63);
    float ch = (slot_hi == 0) ? a0 : (slot_hi == 1) ? a1 : (slot_hi == 2) ? a2 : a3;
    float cl = (slot_lo == 0) ? a0 : (slot_lo == 1) ? a1 : (slot_lo == 2) ? a2 : a3;
    float vh = __shfl(ch, lane_hi, 64);
    float vl = __shfl(cl, lane_lo, 64);
    if (lane == 0) {
        const float s = vh + vl;
        const float loss = (s > 0.f) ? -(__logf(s) + ls) : 0.0f; // zero_infinity
        ws_loss[b] = loss;
    }
}

// out = (sum_j focal_j / (B*L)) * (sum_b loss_b / B)
__global__ __launch_bounds__(256) void ctc_finalize(
        const float* __restrict__ ws_mean, const float* __restrict__ ws_loss,
        const int* __restrict__ tgt, float* __restrict__ out) {
    const int tid = threadIdx.x;
    float fsum = 0.f;
#pragma unroll
    for (int k = 0; k < (B_DIM * L_DIM) / 256; ++k) {
        const int j = tid + k * 256;
        const int b = j / L_DIM;
        const int c = tgt[j];
        const float p = ws_mean[b * C_DIM + c];
        const float w = 1.0f - p;
        fsum += w * w;
    }
    float lsum = (tid < B_DIM) ? ws_loss[tid] : 0.f;
#pragma unroll
    for (int off = 32; off > 0; off >>= 1) {
        fsum += __shfl_down(fsum, off, 64);
        lsum += __shfl_down(lsum, off, 64);
    }
    __shared__ float sf[4], sl[4];
    const int w = tid >> 6;
    if ((tid & 63) == 0) { sf[w] = fsum; sl[w] = lsum; }
    __syncthreads();
    if (tid == 0) {
        const float F = sf[0] + sf[1] + sf[2] + sf[3];
        const float Lo = sl[0] + sl[1] + sl[2] + sl[3];
        out[0] = (F / (float)(B_DIM * L_DIM)) * (Lo / (float)B_DIM);
    }
}

extern "C" void kernel_launch(void* const* d_in, const int* in_sizes, int n_in,
                              void* d_out, int out_size, void* d_ws, size_t ws_size,
                              hipStream_t stream) {
    const float* lp = (const float*)d_in[0];
    const int* tgt = (const int*)d_in[1];
    const int* il = (const int*)d_in[2];
    const int* tl = (const int*)d_in[3];
    float* ws_mean = (float*)d_ws;               // B*C floats (atomicAdd target)
    float* ws_loss = ws_mean + B_DIM * C_DIM;    // B floats

    hipMemsetAsync(ws_mean, 0, B_DIM * C_DIM * sizeof(float), stream);
    ctc_fused<<<dim3(B_DIM + MEAN_SLICES * B_DIM), dim3(256), 0, stream>>>(
        lp, tgt, il, tl, ws_mean, ws_loss);
    ctc_finalize<<<dim3(1), dim3(256), 0, stream>>>(ws_mean, ws_loss, tgt, (float*)d_out);
}

// Round 5
// 175.271 us; speedup vs baseline: 3.5145x; 1.1571x over previous
//
#include <hip/hip_runtime.h>
#include <cstdint>

#define T_DIM 1000
#define B_DIM 64
#define C_DIM 256
#define L_DIM 100
#define S_DIM (2 * L_DIM + 1) /* 201 */
#define RING 16
#define MEAN_SLICES 8
#define MEAN_ROWS (T_DIM / MEAN_SLICES) /* 125 */

// DPP cross-lane (VALU-rate; replaces 120-cyc LDS bpermute/shfl on the chain).
// ctrl must be a literal: wave_shr:1=0x138, row_shr:n=0x110|n,
// row_bcast:15=0x142, row_bcast:31=0x143. bound_ctrl=true -> invalid lanes read 0.
#define DPP_I(x, ctrl) __builtin_amdgcn_update_dpp(0, (x), (ctrl), 0xF, 0xF, true)
#define DPP_F(x, ctrl) __int_as_float(DPP_I(__float_as_int(x), (ctrl)))

// Wave-wide max of non-negative values via gfx9 DPP ladder; result broadcast
// from lane 63 (reduction order doesn't change an exact max).
__device__ __forceinline__ float wave_max_dpp(float x) {
    x = fmaxf(x, DPP_F(x, 0x111)); // row_shr:1
    x = fmaxf(x, DPP_F(x, 0x112)); // row_shr:2
    x = fmaxf(x, DPP_F(x, 0x114)); // row_shr:4
    x = fmaxf(x, DPP_F(x, 0x118)); // row_shr:8  -> lane15 of each row has row max
    x = fmaxf(x, DPP_F(x, 0x142)); // row_bcast:15
    x = fmaxf(x, DPP_F(x, 0x143)); // row_bcast:31 -> lane 63 has wave max
    return __int_as_float(__builtin_amdgcn_readlane(__float_as_int(x), 63));
}

// Fused kernel:
//   blocks [0,B): CTC alpha recursion, linear space, global wave renorm (R3 math).
//   blocks [B, B+8*B): mean-over-time exp(log_probs) -> atomicAdd ws_mean.
__global__ __launch_bounds__(256) void ctc_fused(
        const float* __restrict__ lp,       // (T,B,C)
        const int* __restrict__ tgt,        // (B*L,)
        const int* __restrict__ il,         // (B,)
        const int* __restrict__ tl,         // (B,)
        float* __restrict__ ws_mean,        // (B,C) zero-initialized
        float* __restrict__ ws_loss) {      // (B,)
    const int blk = blockIdx.x;
    const uint32_t rstride = B_DIM * C_DIM;

    if (blk >= B_DIM) {
        const int mb = blk - B_DIM;
        const int b = mb >> 3;
        const int slice = mb & 7;
        const int c = threadIdx.x;
        const float* p = lp + (size_t)b * C_DIM + c + (size_t)(slice * MEAN_ROWS) * rstride;
        float s0 = 0.f, s1 = 0.f, s2 = 0.f, s3 = 0.f, s4 = 0.f;
        for (int t = 0; t < MEAN_ROWS; t += 5) {
            s0 += __expf(p[(size_t)(t + 0) * rstride]);
            s1 += __expf(p[(size_t)(t + 1) * rstride]);
            s2 += __expf(p[(size_t)(t + 2) * rstride]);
            s3 += __expf(p[(size_t)(t + 3) * rstride]);
            s4 += __expf(p[(size_t)(t + 4) * rstride]);
        }
        atomicAdd(&ws_mean[b * C_DIM + c], (s0 + s1 + s2 + s3 + s4) * (1.0f / T_DIM));
        return;
    }

    // ---- CTC pass: one wave (threads 0..63) per batch sample ----
    if (threadIdx.x >= 64) return;
    const int b = blk;
    const int lane = threadIdx.x;
    const int* trow = tgt + b * L_DIM;
    const int ilen = il[b];
    const int tlen = tl[b];

    const int i1 = 2 * lane;
    const int i3 = 2 * lane + 1;
    const int c1 = (i1 < L_DIM) ? trow[i1] : 0;
    const int c3 = (i3 < L_DIM) ? trow[i3] : 0;
    const int c1m = (i1 >= 1 && i1 - 1 < L_DIM) ? trow[i1 - 1] : -1;
    const float m1 = ((i1 >= 1) && (c1 != c1m)) ? 1.0f : 0.0f;
    const float m3 = (c3 != c1) ? 1.0f : 0.0f;

    // invalid states (s >= S) must be zeroed at each renorm (R2 lesson)
    const float f0 = (4 * lane + 0 < S_DIM) ? 1.0f : 0.0f;
    const float f1 = (4 * lane + 1 < S_DIM) ? 1.0f : 0.0f;
    const float f2 = (4 * lane + 2 < S_DIM) ? 1.0f : 0.0f;
    const float f3 = (4 * lane + 3 < S_DIM) ? 1.0f : 0.0f;

    const float* base = lp + (size_t)b * C_DIM;

    float a0 = 0.f, a1 = 0.f, a2 = 0.f, a3 = 0.f;
    {
        float i0 = __expf(base[0]);
        float i1v = __expf(base[c1]);
        if (lane == 0) { a0 = i0; a1 = i1v; }
    }
    float ls = 0.f; // accumulated log scale

    // identical arithmetic to R3's renorm: same max, same rcp, same logf
#define RENORM() do {                                                     \
        a0 *= f0; a1 *= f1; a2 *= f2; a3 *= f3;                           \
        const float mx = wave_max_dpp(fmaxf(fmaxf(a0, a1), fmaxf(a2, a3))); \
        const float inv = __builtin_amdgcn_rcpf(mx);                      \
        ls -= __logf(inv);                                                \
        a0 *= inv; a1 *= inv; a2 *= inv; a3 *= inv;                       \
    } while (0)

    // register ring prefetch of raw log-prob values, 16 steps deep
    float rb[RING], r1[RING], r3[RING];
#pragma unroll
    for (int d = 0; d < RING; ++d) {
        int t = 1 + d; t = (t < ilen) ? t : (ilen - 1);
        const uint32_t ro = (uint32_t)t * rstride;
        rb[d] = base[ro];
        r1[d] = base[ro + (uint32_t)c1];
        r3[d] = base[ro + (uint32_t)c3];
    }

    int base_t = 1;
    for (; base_t + RING <= ilen; base_t += RING) {
#pragma unroll
        for (int d = 0; d < RING; ++d) {
            const float pb  = __expf(rb[d]);
            const float p1e = __expf(r1[d]);
            const float p3e = __expf(r3[d]);
            {
                int tp = base_t + d + RING; tp = (tp < ilen) ? tp : (ilen - 1);
                const uint32_t ro = (uint32_t)tp * rstride;
                rb[d] = base[ro];
                r1[d] = base[ro + (uint32_t)c1];
                r3[d] = base[ro + (uint32_t)c3];
            }
            const float p3 = DPP_F(a3, 0x138); // prev lane's a3; lane0 -> 0
            const float a01 = a0 + a1;
            const float n0 = (a0 + p3) * pb;
            const float n1 = fmaf(m1, p3, a01) * p1e;
            const float n2 = (a2 + a1) * pb;
            const float n3 = (fmaf(m3, a1, a2) + a3) * p3e;
            a0 = n0; a1 = n1; a2 = n2; a3 = n3;
            if ((d & 7) == 7) RENORM();
        }
    }

    // tail (< RING steps), values already resident in the ring
#pragma unroll
    for (int d = 0; d < RING - 1; ++d) {
        const int t = base_t + d;
        if (t < ilen) {
            const float pb  = __expf(rb[d]);
            const float p1e = __expf(r1[d]);
            const float p3e = __expf(r3[d]);
            const float p3 = DPP_F(a3, 0x138);
            const float a01 = a0 + a1;
            const float n0 = (a0 + p3) * pb;
            const float n1 = fmaf(m1, p3, a01) * p1e;
            const float n2 = (a2 + a1) * pb;
            const float n3 = (fmaf(m3, a1, a2) + a3) * p3e;
            a0 = n0; a1 = n1; a2 = n2; a3 = n3;
            if ((d & 7) == 7) RENORM();
        }
    }
#undef RENORM

    // final: ll = log(alpha[2tl] + alpha[2tl-1]) + ls
    const int s_hi = 2 * tlen;
    const int s_lo = 2 * tlen - 1;
    const int slot_hi = s_hi & 3, lane_hi = min(s_hi >> 2, 63);
    const int slot_lo = s_lo & 3, lane_lo = min(s_lo >> 2, 63);
    float ch = (slot_hi == 0) ? a0 : (slot_hi == 1) ? a1 : (slot_hi == 2) ? a2 : a3;
    float cl = (slot_lo == 0) ? a0 : (slot_lo == 1) ? a1 : (slot_lo == 2) ? a2 : a3;
    const float vh = __shfl(ch, lane_hi, 64);
    const float vl = __shfl(cl, lane_lo, 64);
    if (lane == 0) {
        const float s = vh + vl;
        const float loss = (s > 0.f) ? -(__logf(s) + ls) : 0.0f; // zero_infinity
        ws_loss[b] = loss;
    }
}

// out = (sum_j focal_j / (B*L)) * (sum_b loss_b / B)
__global__ __launch_bounds__(256) void ctc_finalize(
        const float* __restrict__ ws_mean, const float* __restrict__ ws_loss,
        const int* __restrict__ tgt, float* __restrict__ out) {
    const int tid = threadIdx.x;
    float fsum = 0.f;
#pragma unroll
    for (int k = 0; k < (B_DIM * L_DIM) / 256; ++k) {
        const int j = tid + k * 256;
        const int b = j / L_DIM;
        const int c = tgt[j];
        const float p = ws_mean[b * C_DIM + c];
        const float w = 1.0f - p;
        fsum += w * w;
    }
    float lsum = (tid < B_DIM) ? ws_loss[tid] : 0.f;
#pragma unroll
    for (int off = 32; off > 0; off >>= 1) {
        fsum += __shfl_down(fsum, off, 64);
        lsum += __shfl_down(lsum, off, 64);
    }
    __shared__ float sf[4], sl[4];
    const int w = tid >> 6;
    if ((tid & 63) == 0) { sf[w] = fsum; sl[w] = lsum; }
    __syncthreads();
    if (tid == 0) {
        const float F = sf[0] + sf[1] + sf[2] + sf[3];
        const float Lo = sl[0] + sl[1] + sl[2] + sl[3];
        out[0] = (F / (float)(B_DIM * L_DIM)) * (Lo / (float)B_DIM);
    }
}

extern "C" void kernel_launch(void* const* d_in, const int* in_sizes, int n_in,
                              void* d_out, int out_size, void* d_ws, size_t ws_size,
                              hipStream_t stream) {
    const float* lp = (const float*)d_in[0];
    const int* tgt = (const int*)d_in[1];
    const int* il = (const int*)d_in[2];
    const int* tl = (const int*)d_in[3];
    float* ws_mean = (float*)d_ws;               // B*C floats (atomicAdd target)
    float* ws_loss = ws_mean + B_DIM * C_DIM;    // B floats

    hipMemsetAsync(ws_mean, 0, B_DIM * C_DIM * sizeof(float), stream);
    ctc_fused<<<dim3(B_DIM + MEAN_SLICES * B_DIM), dim3(256), 0, stream>>>(
        lp, tgt, il, tl, ws_mean, ws_loss);
    ctc_finalize<<<dim3(1), dim3(256), 0, stream>>>(ws_mean, ws_loss, tgt, (float*)d_out);
}

// Round 6
// 166.740 us; speedup vs baseline: 3.6943x; 1.0512x over previous
//
#include <hip/hip_runtime.h>
#include <cstdint>

#define T_DIM 1000
#define B_DIM 64
#define C_DIM 256
#define L_DIM 100
#define S_DIM (2 * L_DIM + 1) /* 201 */
#define CH 16                 /* chunk: steps per burst */
#define MEAN_SLICES 8
#define MEAN_ROWS (T_DIM / MEAN_SLICES) /* 125 */

// DPP cross-lane (VALU-rate). wave_shr:1=0x138, row_shr:n=0x110|n,
// row_bcast:15=0x142, row_bcast:31=0x143. bound_ctrl=true -> invalid lanes read 0.
#define DPP_I(x, ctrl) __builtin_amdgcn_update_dpp(0, (x), (ctrl), 0xF, 0xF, true)
#define DPP_F(x, ctrl) __int_as_float(DPP_I(__float_as_int(x), (ctrl)))

// Wave-wide max of non-negative values; exact, order-independent.
__device__ __forceinline__ float wave_max_dpp(float x) {
    x = fmaxf(x, DPP_F(x, 0x111)); // row_shr:1
    x = fmaxf(x, DPP_F(x, 0x112)); // row_shr:2
    x = fmaxf(x, DPP_F(x, 0x114)); // row_shr:4
    x = fmaxf(x, DPP_F(x, 0x118)); // row_shr:8
    x = fmaxf(x, DPP_F(x, 0x142)); // row_bcast:15
    x = fmaxf(x, DPP_F(x, 0x143)); // row_bcast:31 -> lane 63 has wave max
    return __int_as_float(__builtin_amdgcn_readlane(__float_as_int(x), 63));
}

// Fused kernel:
//   blocks [0,B): CTC alpha recursion, linear space, wave renorm (R5 math,
//                 bit-identical), chunked ping-pong register prefetch.
//   blocks [B, B+8*B): mean-over-time exp(log_probs) -> atomicAdd ws_mean.
// __launch_bounds__(256,1): allow ~512 VGPR/thread so the 2x48-float prefetch
// buffers stay register-resident (at (256,default) the compiler remat-sank the
// prefetch loads to their uses -> VGPR=36, zero effective prefetch, R3/R5).
__global__ __launch_bounds__(256, 1) void ctc_fused(
        const float* __restrict__ lp,       // (T,B,C)
        const int* __restrict__ tgt,        // (B*L,)
        const int* __restrict__ il,         // (B,)
        const int* __restrict__ tl,         // (B,)
        float* __restrict__ ws_mean,        // (B,C) zero-initialized
        float* __restrict__ ws_loss) {      // (B,)
    const int blk = blockIdx.x;
    const uint32_t rstride = B_DIM * C_DIM;

    if (blk >= B_DIM) {
        const int mb = blk - B_DIM;
        const int b = mb >> 3;
        const int slice = mb & 7;
        const int c = threadIdx.x;
        const float* p = lp + (size_t)b * C_DIM + c + (size_t)(slice * MEAN_ROWS) * rstride;
        float s0 = 0.f, s1 = 0.f, s2 = 0.f, s3 = 0.f, s4 = 0.f;
        for (int t = 0; t < MEAN_ROWS; t += 5) {
            s0 += __expf(p[(size_t)(t + 0) * rstride]);
            s1 += __expf(p[(size_t)(t + 1) * rstride]);
            s2 += __expf(p[(size_t)(t + 2) * rstride]);
            s3 += __expf(p[(size_t)(t + 3) * rstride]);
            s4 += __expf(p[(size_t)(t + 4) * rstride]);
        }
        atomicAdd(&ws_mean[b * C_DIM + c], (s0 + s1 + s2 + s3 + s4) * (1.0f / T_DIM));
        return;
    }

    // ---- CTC pass: one wave (threads 0..63) per batch sample ----
    if (threadIdx.x >= 64) return;
    const int b = blk;
    const int lane = threadIdx.x;
    const int* trow = tgt + b * L_DIM;
    const int ilen = il[b];
    const int tlen = tl[b];

    const int i1 = 2 * lane;
    const int i3 = 2 * lane + 1;
    const int c1 = (i1 < L_DIM) ? trow[i1] : 0;
    const int c3 = (i3 < L_DIM) ? trow[i3] : 0;
    const int c1m = (i1 >= 1 && i1 - 1 < L_DIM) ? trow[i1 - 1] : -1;
    const float m1 = ((i1 >= 1) && (c1 != c1m)) ? 1.0f : 0.0f;
    const float m3 = (c3 != c1) ? 1.0f : 0.0f;

    // invalid states (s >= S) must be zeroed at each renorm (R2 lesson)
    const float f0 = (4 * lane + 0 < S_DIM) ? 1.0f : 0.0f;
    const float f1 = (4 * lane + 1 < S_DIM) ? 1.0f : 0.0f;
    const float f2 = (4 * lane + 2 < S_DIM) ? 1.0f : 0.0f;
    const float f3 = (4 * lane + 3 < S_DIM) ? 1.0f : 0.0f;

    const float* base = lp + (size_t)b * C_DIM;

    float a0 = 0.f, a1 = 0.f, a2 = 0.f, a3 = 0.f;
    {
        float i0 = __expf(base[0]);
        float i1v = __expf(base[c1]);
        if (lane == 0) { a0 = i0; a1 = i1v; }
    }
    float ls = 0.f; // accumulated log scale

#define RENORM() do {                                                       \
        a0 *= f0; a1 *= f1; a2 *= f2; a3 *= f3;                             \
        const float mx = wave_max_dpp(fmaxf(fmaxf(a0, a1), fmaxf(a2, a3))); \
        const float inv = __builtin_amdgcn_rcpf(mx);                        \
        ls -= __logf(inv);                                                  \
        a0 *= inv; a1 *= inv; a2 *= inv; a3 *= inv;                         \
    } while (0)

    // ping-pong prefetch buffers: 2 x (16 steps x 3 values) = 96 floats
    float Ab[CH], A1[CH], A3[CH], Bb[CH], B1[CH], B3[CH];

    // straight-line burst load of one chunk (clamped t, unconditional)
    auto burst = [&](float* vb, float* v1, float* v3, int tstart) {
#pragma unroll
        for (int d = 0; d < CH; ++d) {
            int tp = tstart + d; tp = (tp < ilen) ? tp : (ilen - 1);
            const uint32_t ro = (uint32_t)tp * rstride;
            vb[d] = base[ro];
            v1[d] = base[ro + (uint32_t)c1];
            v3[d] = base[ro + (uint32_t)c3];
        }
    };

    // one recursion step (bit-identical to R5)
    auto step = [&](float lb, float l1, float l3) {
        const float pb  = __expf(lb);
        const float p1e = __expf(l1);
        const float p3e = __expf(l3);
        const float p3 = DPP_F(a3, 0x138); // prev lane's a3; lane0 -> 0
        const float a01 = a0 + a1;
        const float n0 = (a0 + p3) * pb;
        const float n1 = fmaf(m1, p3, a01) * p1e;
        const float n2 = (a2 + a1) * pb;
        const float n3 = (fmaf(m3, a1, a2) + a3) * p3e;
        a0 = n0; a1 = n1; a2 = n2; a3 = n3;
    };

    // unguarded 16-step chunk; renorm at d&7==7 (chunk starts at t===1 mod 16,
    // so this is exactly t%8==0 — same renorm set as R5: t=8,16,...,992)
    auto chunk16 = [&](const float* vb, const float* v1, const float* v3) {
#pragma unroll
        for (int d = 0; d < CH; ++d) {
            step(vb[d], v1[d], v3[d]);
            if ((d & 7) == 7) RENORM();
        }
    };

    burst(Ab, A1, A3, 1);
    burst(Bb, B1, B3, 1 + CH);

    int t = 1;
    for (; t + 2 * CH <= ilen; t += 2 * CH) {
        chunk16(Ab, A1, A3);            // steps t .. t+15 (all < ilen)
        burst(Ab, A1, A3, t + 2 * CH);  // prefetch t+32 .. t+47 (in flight over next chunk)
        chunk16(Bb, B1, B3);            // steps t+16 .. t+31
        burst(Bb, B1, B3, t + 3 * CH);  // prefetch t+48 .. t+63
    }

    // epilogue: <= 31 remaining steps, buffers already loaded (clamped)
#pragma unroll
    for (int d = 0; d < CH; ++d) {
        const int tt = t + d;
        if (tt < ilen) {
            step(Ab[d], A1[d], A3[d]);
            if ((d & 7) == 7) RENORM();
        }
    }
#pragma unroll
    for (int d = 0; d < CH; ++d) {
        const int tt = t + CH + d;
        if (tt < ilen) {
            step(Bb[d], B1[d], B3[d]);
            if ((d & 7) == 7) RENORM();
        }
    }
#undef RENORM

    // final: ll = log(alpha[2tl] + alpha[2tl-1]) + ls
    const int s_hi = 2 * tlen;
    const int s_lo = 2 * tlen - 1;
    const int slot_hi = s_hi & 3, lane_hi = min(s_hi >> 2, 63);
    const int slot_lo = s_lo & 3, lane_lo = min(s_lo >> 2, 63);
    float ch = (slot_hi == 0) ? a0 : (slot_hi == 1) ? a1 : (slot_hi == 2) ? a2 : a3;
    float cl = (slot_lo == 0) ? a0 : (slot_lo == 1) ? a1 : (slot_lo == 2) ? a2 : a3;
    const float vh = __shfl(ch, lane_hi, 64);
    const float vl = __shfl(cl, lane_lo, 64);
    if (lane == 0) {
        const float s = vh + vl;
        const float loss = (s > 0.f) ? -(__logf(s) + ls) : 0.0f; // zero_infinity
        ws_loss[b] = loss;
    }
}

// out = (sum_j focal_j / (B*L)) * (sum_b loss_b / B)
__global__ __launch_bounds__(256) void ctc_finalize(
        const float* __restrict__ ws_mean, const float* __restrict__ ws_loss,
        const int* __restrict__ tgt, float* __restrict__ out) {
    const int tid = threadIdx.x;
    float fsum = 0.f;
#pragma unroll
    for (int k = 0; k < (B_DIM * L_DIM) / 256; ++k) {
        const int j = tid + k * 256;
        const int b = j / L_DIM;
        const int c = tgt[j];
        const float p = ws_mean[b * C_DIM + c];
        const float w = 1.0f - p;
        fsum += w * w;
    }
    float lsum = (tid < B_DIM) ? ws_loss[tid] : 0.f;
#pragma unroll
    for (int off = 32; off > 0; off >>= 1) {
        fsum += __shfl_down(fsum, off, 64);
        lsum += __shfl_down(lsum, off, 64);
    }
    __shared__ float sf[4], sl[4];
    const int w = tid >> 6;
    if ((tid & 63) == 0) { sf[w] = fsum; sl[w] = lsum; }
    __syncthreads();
    if (tid == 0) {
        const float F = sf[0] + sf[1] + sf[2] + sf[3];
        const float Lo = sl[0] + sl[1] + sl[2] + sl[3];
        out[0] = (F / (float)(B_DIM * L_DIM)) * (Lo / (float)B_DIM);
    }
}

extern "C" void kernel_launch(void* const* d_in, const int* in_sizes, int n_in,
                              void* d_out, int out_size, void* d_ws, size_t ws_size,
                              hipStream_t stream) {
    const float* lp = (const float*)d_in[0];
    const int* tgt = (const int*)d_in[1];
    const int* il = (const int*)d_in[2];
    const int* tl = (const int*)d_in[3];
    float* ws_mean = (float*)d_ws;               // B*C floats (atomicAdd target)
    float* ws_loss = ws_mean + B_DIM * C_DIM;    // B floats

    hipMemsetAsync(ws_mean, 0, B_DIM * C_DIM * sizeof(float), stream);
    ctc_fused<<<dim3(B_DIM + MEAN_SLICES * B_DIM), dim3(256), 0, stream>>>(
        lp, tgt, il, tl, ws_mean, ws_loss);
    ctc_finalize<<<dim3(1), dim3(256), 0, stream>>>(ws_mean, ws_loss, tgt, (float*)d_out);
}